// Round 1
// baseline (704.507 us; speedup 1.0000x reference)
//
#include <hip/hip_runtime.h>
#include <stdint.h>

#define NN 40000            // N_NODES
#define E_IN 2560000        // input edges
#define E2 5120000          // 2*E_IN, padded output edge count
#define CAP 2048            // per-row bucket capacity (Poisson(64): overflow impossible)
#define SCAN_T 1024

// ---------------- K0: fill output padding: indices=-1, attrs=0 ----------------
__global__ void k_fill(float4* __restrict__ out) {
    int i = blockIdx.x * blockDim.x + threadIdx.x;      // over 3*E2/4 = 3,840,000
    if (i >= 3 * E2 / 4) return;
    float v = (i < 2 * E2 / 4) ? -1.0f : 0.0f;
    out[i] = make_float4(v, v, v, v);
}

// ---------------- K1: per-row histogram of kept symmetrized entries ----------------
__global__ void k_hist(const int* __restrict__ ei, const float* __restrict__ ea,
                       const float* __restrict__ t, int* __restrict__ rowCount) {
    int i = blockIdx.x * blockDim.x + threadIdx.x;
    if (i >= E_IN) return;
    float a = ea[i];
    if (a <= t[0]) {
        int r = ei[i];
        int c = ei[E_IN + i];
        atomicAdd(&rowCount[r], 1);
        atomicAdd(&rowCount[c], 1);
    }
}

// ---------------- single-block exclusive scan (n up to ~40k) ----------------
__global__ void k_scan(const int* __restrict__ in, int n, int* __restrict__ outExcl,
                       int* __restrict__ outCursor, float* __restrict__ totalDst) {
    __shared__ int sdata[SCAN_T];
    __shared__ int carryS;
    if (threadIdx.x == 0) carryS = 0;
    __syncthreads();
    for (int base = 0; base < n; base += SCAN_T) {
        int i = base + threadIdx.x;
        int v = (i < n) ? in[i] : 0;
        sdata[threadIdx.x] = v;
        __syncthreads();
        for (int off = 1; off < SCAN_T; off <<= 1) {
            int add = (threadIdx.x >= off) ? sdata[threadIdx.x - off] : 0;
            __syncthreads();
            sdata[threadIdx.x] += add;
            __syncthreads();
        }
        int excl = sdata[threadIdx.x] - v + carryS;
        if (i < n) {
            outExcl[i] = excl;
            if (outCursor) outCursor[i] = excl;
        }
        int chunkTot = sdata[SCAN_T - 1];
        __syncthreads();                 // everyone read carryS & chunkTot
        if (threadIdx.x == 0) carryS += chunkTot;
        __syncthreads();
    }
    if (threadIdx.x == 0) {
        outExcl[n] = carryS;
        if (totalDst) totalDst[0] = (float)carryS;   // num_edges as f32
    }
}

// ---------------- K3: scatter kept entries into row buckets ----------------
__global__ void k_scatter(const int* __restrict__ ei, const float* __restrict__ ea,
                          const float* __restrict__ t, int* __restrict__ rowCursor,
                          int* __restrict__ colS, float* __restrict__ attrS) {
    int i = blockIdx.x * blockDim.x + threadIdx.x;
    if (i >= E_IN) return;
    float a = ea[i];
    if (a <= t[0]) {
        int r = ei[i];
        int c = ei[E_IN + i];
        int p1 = atomicAdd(&rowCursor[r], 1);
        colS[p1] = c; attrS[p1] = a;
        int p2 = atomicAdd(&rowCursor[c], 1);
        colS[p2] = r; attrS[p2] = a;
    }
}

// ---------------- K4: per-row bitonic sort by col + dedupe/sum + compact ----------------
__global__ void __launch_bounds__(128) k_rowsort(const int* __restrict__ rowOffset,
                                                 const int* __restrict__ rowCount,
                                                 int* __restrict__ colS,
                                                 float* __restrict__ attrS,
                                                 int* __restrict__ uniqueCount) {
    int r = blockIdx.x;
    int n = rowCount[r];
    if (n > CAP) n = CAP;   // unreachable for this input distribution; safety clamp
    if (n <= 0) { if (threadIdx.x == 0) uniqueCount[r] = 0; return; }
    int base = rowOffset[r];

    __shared__ int sc[CAP];
    __shared__ float sa[CAP];
    __shared__ int part[128];

    int m = 1; while (m < n) m <<= 1;
    for (int i = threadIdx.x; i < m; i += 128) {
        if (i < n) { sc[i] = colS[base + i]; sa[i] = attrS[base + i]; }
        else       { sc[i] = 0x7fffffff;     sa[i] = 0.0f; }
    }
    __syncthreads();

    for (int k = 2; k <= m; k <<= 1) {
        for (int j = k >> 1; j > 0; j >>= 1) {
            for (int i = threadIdx.x; i < m; i += 128) {
                int ixj = i ^ j;
                if (ixj > i) {
                    bool up = ((i & k) == 0);
                    int c1 = sc[i], c2 = sc[ixj];
                    if ((c1 > c2) == up) {
                        sc[i] = c2; sc[ixj] = c1;
                        float tf = sa[i]; sa[i] = sa[ixj]; sa[ixj] = tf;
                    }
                }
            }
            __syncthreads();
        }
    }

    // head-flag count per thread chunk
    int chunk = (m + 127) / 128;
    int s0 = threadIdx.x * chunk; if (s0 > m) s0 = m;
    int s1 = s0 + chunk;          if (s1 > m) s1 = m;
    int cnt = 0;
    for (int i = s0; i < s1; i++)
        if (i < n && (i == 0 || sc[i] != sc[i - 1])) cnt++;
    part[threadIdx.x] = cnt;
    __syncthreads();
    for (int off = 1; off < 128; off <<= 1) {
        int add = (threadIdx.x >= off) ? part[threadIdx.x - off] : 0;
        __syncthreads();
        part[threadIdx.x] += add;
        __syncthreads();
    }
    int pos = part[threadIdx.x] - cnt;   // exclusive prefix
    int total = part[127];

    // sum duplicate runs (rare, short) and write compacted (col,sum) back in place
    for (int i = s0; i < s1; i++) {
        if (i < n && (i == 0 || sc[i] != sc[i - 1])) {
            float s = sa[i];
            for (int q = i + 1; q < n && sc[q] == sc[i]; q++) s += sa[q];
            colS[base + pos]  = sc[i];
            attrS[base + pos] = s;
            pos++;
        }
    }
    if (threadIdx.x == 0) uniqueCount[r] = total;
}

// ---------------- K6: write compacted output (row, col, attr as f32) ----------------
__global__ void k_write(const int* __restrict__ rowOffset, const int* __restrict__ uniqueCount,
                        const int* __restrict__ outBase, const int* __restrict__ colS,
                        const float* __restrict__ attrS, float* __restrict__ out) {
    int r = blockIdx.x;
    int n = uniqueCount[r];
    int src = rowOffset[r];
    int dst = outBase[r];
    float rf = (float)r;
    for (int j = threadIdx.x; j < n; j += blockDim.x) {
        int p = dst + j;
        out[p]            = rf;
        out[E2 + p]       = (float)colS[src + j];
        out[2 * E2 + p]   = attrS[src + j];
    }
}

extern "C" void kernel_launch(void* const* d_in, const int* in_sizes, int n_in,
                              void* d_out, int out_size, void* d_ws, size_t ws_size,
                              hipStream_t stream) {
    const int*   ei  = (const int*)d_in[0];    // [2,E] row-major: rows then cols
    const float* ea  = (const float*)d_in[1];  // [E]
    const float* t   = (const float*)d_in[2];  // [1]
    float* out = (float*)d_out;                // 2*E2 indices + E2 attrs + 1 count, all f32

    // workspace layout (~41.8 MB)
    int* rowCount    = (int*)d_ws;                 // 40000
    int* uniqueCount = rowCount + NN;              // 40000 (adjacent -> one memset)
    int* rowOffset   = uniqueCount + NN;           // 40001
    int* rowCursor   = rowOffset + NN + 1;         // 40000
    int* outBase     = rowCursor + NN;             // 40001
    int* colS  = (int*)(((uintptr_t)(outBase + NN + 1) + 15) & ~(uintptr_t)15);   // E2
    float* attrS = (float*)(colS + E2);                                           // E2

    hipMemsetAsync(rowCount, 0, (size_t)2 * NN * sizeof(int), stream);

    k_fill<<<(3 * E2 / 4 + 255) / 256, 256, 0, stream>>>((float4*)out);
    k_hist<<<(E_IN + 255) / 256, 256, 0, stream>>>(ei, ea, t, rowCount);
    k_scan<<<1, SCAN_T, 0, stream>>>(rowCount, NN, rowOffset, rowCursor, nullptr);
    k_scatter<<<(E_IN + 255) / 256, 256, 0, stream>>>(ei, ea, t, rowCursor, colS, attrS);
    k_rowsort<<<NN, 128, 0, stream>>>(rowOffset, rowCount, colS, attrS, uniqueCount);
    k_scan<<<1, SCAN_T, 0, stream>>>(uniqueCount, NN, outBase, nullptr, out + (size_t)3 * E2);
    k_write<<<NN, 64, 0, stream>>>(rowOffset, uniqueCount, outBase, colS, attrS, out);
}

// Round 2
// 597.444 us; speedup vs baseline: 1.1792x; 1.1792x over previous
//
#include <hip/hip_runtime.h>
#include <stdint.h>

#define NN 40000            // N_NODES
#define E_IN 2560000        // input edges
#define E2 5120000          // 2*E_IN, padded output edge count
#define CAP 256             // per-row bucket capacity (Poisson(64): P(>=256)~1e-50)
#define SCAN_T 1024
#define SCAN_PER 40         // 1024*40 = 40960 >= 40001

// ---------------- K0: fill output padding: indices=-1, attrs=0 ----------------
__global__ void k_fill(float4* __restrict__ out) {
    int i = blockIdx.x * blockDim.x + threadIdx.x;      // over 3*E2/4 = 3,840,000
    if (i >= 3 * E2 / 4) return;
    float v = (i < 2 * E2 / 4) ? -1.0f : 0.0f;
    out[i] = make_float4(v, v, v, v);
}

// ---------------- K1: per-row histogram of kept symmetrized entries ----------------
__global__ void k_hist(const int* __restrict__ ei, const float* __restrict__ ea,
                       const float* __restrict__ t, int* __restrict__ rowCount) {
    int i = blockIdx.x * blockDim.x + threadIdx.x;
    if (i >= E_IN) return;
    float a = ea[i];
    if (a <= t[0]) {
        int r = ei[i];
        int c = ei[E_IN + i];
        atomicAdd(&rowCount[r], 1);
        atomicAdd(&rowCount[c], 1);
    }
}

// ---------------- K2: single-pass single-block exclusive scan over n<=40960 ----------------
// Each thread owns SCAN_PER contiguous elements in registers; one 1024-wide
// Hillis-Steele over per-thread sums (10 steps) instead of 40 serialized chunks.
__global__ void __launch_bounds__(SCAN_T) k_scan(const int* __restrict__ in, int n,
                                                 int* __restrict__ outExcl,
                                                 int* __restrict__ outCursor,
                                                 float* __restrict__ totalDst) {
    __shared__ int partial[SCAN_T];
    int tid = threadIdx.x;
    int start = tid * SCAN_PER;
    int vals[SCAN_PER];
    int sum = 0;
#pragma unroll
    for (int j = 0; j < SCAN_PER; j++) {
        int i = start + j;
        int v = (i < n) ? in[i] : 0;
        vals[j] = sum;          // local exclusive prefix
        sum += v;
    }
    partial[tid] = sum;
    __syncthreads();
    for (int off = 1; off < SCAN_T; off <<= 1) {
        int add = (tid >= off) ? partial[tid - off] : 0;
        __syncthreads();
        partial[tid] += add;
        __syncthreads();
    }
    int base = partial[tid] - sum;   // exclusive prefix of this thread's chunk
#pragma unroll
    for (int j = 0; j < SCAN_PER; j++) {
        int i = start + j;
        if (i < n) {
            int e = base + vals[j];
            outExcl[i] = e;
            if (outCursor) outCursor[i] = e;
        }
    }
    if (tid == SCAN_T - 1) {
        outExcl[n] = partial[SCAN_T - 1];
        if (totalDst) totalDst[0] = (float)partial[SCAN_T - 1];   // num_edges as f32
    }
}

// ---------------- K3: scatter kept entries into row buckets (packed int2) ----------------
__global__ void k_scatter(const int* __restrict__ ei, const float* __restrict__ ea,
                          const float* __restrict__ t, int* __restrict__ rowCursor,
                          int2* __restrict__ pairs) {
    int i = blockIdx.x * blockDim.x + threadIdx.x;
    if (i >= E_IN) return;
    float a = ea[i];
    if (a <= t[0]) {
        int r = ei[i];
        int c = ei[E_IN + i];
        int ab = __float_as_int(a);
        int p1 = atomicAdd(&rowCursor[r], 1);
        pairs[p1] = make_int2(c, ab);
        int p2 = atomicAdd(&rowCursor[c], 1);
        pairs[p2] = make_int2(r, ab);
    }
}

// ---------------- K4: per-row bitonic sort by col + dedupe/sum + compact ----------------
// One wave (64 threads) per row; m <= CAP=256 so <=4 elements/lane.
__global__ void __launch_bounds__(64) k_rowsort(const int* __restrict__ rowOffset,
                                                const int* __restrict__ rowCount,
                                                int2* __restrict__ pairs,
                                                int* __restrict__ uniqueCount) {
    int r = blockIdx.x;
    int n = rowCount[r];
    if (n > CAP) n = CAP;   // statistically unreachable; safety clamp
    if (n <= 0) { if (threadIdx.x == 0) uniqueCount[r] = 0; return; }
    int base = rowOffset[r];

    __shared__ int sc[CAP];
    __shared__ float sa[CAP];
    __shared__ int part[64];

    int m = 1; while (m < n) m <<= 1;
    for (int i = threadIdx.x; i < m; i += 64) {
        if (i < n) { int2 p = pairs[base + i]; sc[i] = p.x; sa[i] = __int_as_float(p.y); }
        else       { sc[i] = 0x7fffffff;       sa[i] = 0.0f; }
    }
    __syncthreads();

    for (int k = 2; k <= m; k <<= 1) {
        for (int j = k >> 1; j > 0; j >>= 1) {
            for (int i = threadIdx.x; i < m; i += 64) {
                int ixj = i ^ j;
                if (ixj > i) {
                    bool up = ((i & k) == 0);
                    int c1 = sc[i], c2 = sc[ixj];
                    if ((c1 > c2) == up) {
                        sc[i] = c2; sc[ixj] = c1;
                        float tf = sa[i]; sa[i] = sa[ixj]; sa[ixj] = tf;
                    }
                }
            }
            __syncthreads();
        }
    }

    // head-flag count per thread chunk (chunk <= 4)
    int chunk = (m + 63) >> 6;
    int s0 = threadIdx.x * chunk; if (s0 > m) s0 = m;
    int s1 = s0 + chunk;          if (s1 > m) s1 = m;
    int cnt = 0;
    for (int i = s0; i < s1; i++)
        if (i < n && (i == 0 || sc[i] != sc[i - 1])) cnt++;
    part[threadIdx.x] = cnt;
    __syncthreads();
    for (int off = 1; off < 64; off <<= 1) {
        int add = (threadIdx.x >= off) ? part[threadIdx.x - off] : 0;
        __syncthreads();
        part[threadIdx.x] += add;
        __syncthreads();
    }
    int pos = part[threadIdx.x] - cnt;   // exclusive prefix
    int total = part[63];

    // sum duplicate runs (rare, short) and write compacted (col,sum) back in place
    for (int i = s0; i < s1; i++) {
        if (i < n && (i == 0 || sc[i] != sc[i - 1])) {
            float s = sa[i];
            for (int q = i + 1; q < n && sc[q] == sc[i]; q++) s += sa[q];
            pairs[base + pos] = make_int2(sc[i], __float_as_int(s));
            pos++;
        }
    }
    if (threadIdx.x == 0) uniqueCount[r] = total;
}

// ---------------- K6: write compacted output (row, col, attr as f32) ----------------
__global__ void __launch_bounds__(64) k_write(const int* __restrict__ rowOffset,
                                              const int* __restrict__ uniqueCount,
                                              const int* __restrict__ outBase,
                                              const int2* __restrict__ pairs,
                                              float* __restrict__ out) {
    int r = blockIdx.x;
    int n = uniqueCount[r];
    int src = rowOffset[r];
    int dst = outBase[r];
    float rf = (float)r;
    for (int j = threadIdx.x; j < n; j += 64) {
        int2 p = pairs[src + j];
        int q = dst + j;
        out[q]            = rf;
        out[E2 + q]       = (float)p.x;
        out[2 * E2 + q]   = __int_as_float(p.y);
    }
}

extern "C" void kernel_launch(void* const* d_in, const int* in_sizes, int n_in,
                              void* d_out, int out_size, void* d_ws, size_t ws_size,
                              hipStream_t stream) {
    const int*   ei  = (const int*)d_in[0];    // [2,E] row-major: rows then cols
    const float* ea  = (const float*)d_in[1];  // [E]
    const float* t   = (const float*)d_in[2];  // [1]
    float* out = (float*)d_out;                // 2*E2 indices + E2 attrs + 1 count, all f32

    // workspace layout (~41.8 MB)
    int* rowCount    = (int*)d_ws;                 // 40000
    int* uniqueCount = rowCount + NN;              // 40000 (adjacent -> one memset)
    int* rowOffset   = uniqueCount + NN;           // 40001
    int* rowCursor   = rowOffset + NN + 1;         // 40000
    int* outBase     = rowCursor + NN;             // 40001
    int2* pairs = (int2*)(((uintptr_t)(outBase + NN + 1) + 15) & ~(uintptr_t)15);  // E2 int2

    hipMemsetAsync(rowCount, 0, (size_t)2 * NN * sizeof(int), stream);

    k_fill<<<(3 * E2 / 4 + 255) / 256, 256, 0, stream>>>((float4*)out);
    k_hist<<<(E_IN + 255) / 256, 256, 0, stream>>>(ei, ea, t, rowCount);
    k_scan<<<1, SCAN_T, 0, stream>>>(rowCount, NN, rowOffset, rowCursor, nullptr);
    k_scatter<<<(E_IN + 255) / 256, 256, 0, stream>>>(ei, ea, t, rowCursor, pairs);
    k_rowsort<<<NN, 64, 0, stream>>>(rowOffset, rowCount, pairs, uniqueCount);
    k_scan<<<1, SCAN_T, 0, stream>>>(uniqueCount, NN, outBase, nullptr, out + (size_t)3 * E2);
    k_write<<<NN, 64, 0, stream>>>(rowOffset, uniqueCount, outBase, pairs, out);
}

// Round 3
// 433.536 us; speedup vs baseline: 1.6250x; 1.3781x over previous
//
#include <hip/hip_runtime.h>
#include <stdint.h>

#define NN 40000            // N_NODES
#define E_IN 2560000        // input edges
#define E2 5120000          // 2*E_IN, padded output size
#define NFINE 1250          // fine buckets: r>>5 (32 rows each)
#define NSB 20              // superbuckets: r>>11 (2048 rows each)
#define SB_SHIFT 11
#define FINES_PER_SB 64
#define P2_TILES 68         // 68*2048 = 139264 >= max superbucket count (23 sigma)
#define CAP3 4096           // fine-bucket sort capacity (mean 2048, sigma 45)
#define PAIRS_CAP 2600000   // total kept entries ~2.56M (25 sigma margin)

typedef unsigned long long ull;

// ---------------- K0: fill output padding: indices=-1, attrs=0 ----------------
__global__ void k_fill(float4* __restrict__ out) {
    int i = blockIdx.x * blockDim.x + threadIdx.x;      // 3*E2/4 = 3,840,000
    if (i >= 3 * E2 / 4) return;
    float v = (i < 2 * E2 / 4) ? -1.0f : 0.0f;
    out[i] = make_float4(v, v, v, v);
}

// ---------------- K1: fine-bucket histogram (LDS sub-hist, few flush atomics) ----------------
__global__ void __launch_bounds__(1024) k_histF(const int* __restrict__ ei,
                                                const float* __restrict__ ea,
                                                const float* __restrict__ t,
                                                int* __restrict__ fineCount) {
    __shared__ int h[NFINE];
    int tid = threadIdx.x;
    for (int j = tid; j < NFINE; j += 1024) h[j] = 0;
    __syncthreads();
    float t0 = t[0];
    for (int i = blockIdx.x * 1024 + tid; i < E_IN; i += 160 * 1024) {
        float a = ea[i];
        if (a <= t0) {
            int r = ei[i], c = ei[E_IN + i];
            atomicAdd(&h[r >> 5], 1);
            atomicAdd(&h[c >> 5], 1);
        }
    }
    __syncthreads();
    for (int j = tid; j < NFINE; j += 1024) {
        int v = h[j];
        if (v) atomicAdd(&fineCount[j], v);
    }
}

// ---------------- K2: single-block exclusive scan over n<=2048 elements ----------------
__global__ void __launch_bounds__(1024) k_scan(const int* __restrict__ in, int n,
                                               int* __restrict__ outExcl,
                                               int* __restrict__ outCursor,
                                               int* __restrict__ sbCursorOut,
                                               float* __restrict__ totalDst) {
    __shared__ int partial[1024];
    int tid = threadIdx.x;
    int i0 = 2 * tid, i1 = 2 * tid + 1;
    int v0 = (i0 < n) ? in[i0] : 0;
    int v1 = (i1 < n) ? in[i1] : 0;
    int sum = v0 + v1;
    partial[tid] = sum;
    __syncthreads();
    for (int off = 1; off < 1024; off <<= 1) {
        int add = (tid >= off) ? partial[tid - off] : 0;
        __syncthreads();
        partial[tid] += add;
        __syncthreads();
    }
    int base = partial[tid] - sum;
    if (i0 < n) { outExcl[i0] = base;      if (outCursor) outCursor[i0] = base; }
    if (i1 < n) { outExcl[i1] = base + v0; if (outCursor) outCursor[i1] = base + v0; }
    if (tid == 1023) {
        outExcl[n] = partial[1023];
        if (totalDst) totalDst[0] = (float)partial[1023];
    }
    if (sbCursorOut) {
        __syncthreads();                       // global writes drained by barrier
        if (tid < NSB) sbCursorOut[tid] = outExcl[tid * FINES_PER_SB];
    }
}

// ---------------- K3: partition pass 1 — entries -> 20 superbuckets ----------------
// Block handles exactly 1024 edges; stages kept entries in LDS grouped by
// superbucket, reserves space with one atomicAdd per bucket, writes runs
// (~51 entries = 408B avg) with consecutive lanes -> coalesced stores.
__global__ void __launch_bounds__(256) k_part1(const int* __restrict__ ei,
                                               const float* __restrict__ ea,
                                               const float* __restrict__ t,
                                               int* __restrict__ sbCursor,
                                               ull* __restrict__ pairs1) {
    __shared__ ull staged[2048];
    __shared__ int cnt[NSB], off[NSB + 1], gbase[NSB];
    int tid = threadIdx.x;
    if (tid < NSB) cnt[tid] = 0;
    __syncthreads();
    float t0 = t[0];
    int tileStart = blockIdx.x * 1024;          // 2500*1024 == E_IN exactly

    ull eA[4], eB[4];
    int rkA[4], rkB[4];
    bool keep[4];
#pragma unroll
    for (int k = 0; k < 4; k++) {
        int i = tileStart + tid + k * 256;
        float a = ea[i];
        keep[k] = (a <= t0);
        if (keep[k]) {
            int r = ei[i], c = ei[E_IN + i];
            unsigned ab = __float_as_uint(a);
            eA[k] = ((ull)(unsigned)r << 48) | ((ull)(unsigned)c << 32) | ab;
            eB[k] = ((ull)(unsigned)c << 48) | ((ull)(unsigned)r << 32) | ab;
            rkA[k] = atomicAdd(&cnt[r >> SB_SHIFT], 1);
            rkB[k] = atomicAdd(&cnt[c >> SB_SHIFT], 1);
        }
    }
    __syncthreads();
    if (tid == 0) {
        int acc = 0;
        for (int s = 0; s < NSB; s++) { off[s] = acc; acc += cnt[s]; }
        off[NSB] = acc;
    }
    __syncthreads();
    if (tid < NSB) gbase[tid] = atomicAdd(&sbCursor[tid], cnt[tid]);
#pragma unroll
    for (int k = 0; k < 4; k++) {
        if (keep[k]) {
            staged[off[(int)(eA[k] >> 59)] + rkA[k]] = eA[k];
            staged[off[(int)(eB[k] >> 59)] + rkB[k]] = eB[k];
        }
    }
    __syncthreads();
    int total = off[NSB];
    for (int i = tid; i < total; i += 256) {
        ull e = staged[i];
        int sb = (int)(e >> 59);
        pairs1[gbase[sb] + (i - off[sb])] = e;
    }
}

// ---------------- K4: partition pass 2 — superbucket -> 64 fine buckets ----------------
__global__ void __launch_bounds__(256) k_part2(const int* __restrict__ fineBase,
                                               int* __restrict__ fineCursor,
                                               const ull* __restrict__ pairs1,
                                               ull* __restrict__ pairs2) {
    int sb = blockIdx.x / P2_TILES;
    int tile = blockIdx.x % P2_TILES;
    int fineFirst = sb * FINES_PER_SB;
    int fineEnd = fineFirst + FINES_PER_SB; if (fineEnd > NFINE) fineEnd = NFINE;
    int nF = fineEnd - fineFirst;
    int sbStart = fineBase[fineFirst];
    int sbEnd = fineBase[fineEnd];
    int start = sbStart + tile * 2048;
    if (start >= sbEnd) return;
    int cntT = sbEnd - start; if (cntT > 2048) cntT = 2048;

    __shared__ ull staged[2048];
    __shared__ int cnt[FINES_PER_SB], off[FINES_PER_SB + 1], gbase[FINES_PER_SB];
    int tid = threadIdx.x;
    if (tid < FINES_PER_SB) cnt[tid] = 0;
    __syncthreads();

    ull e[8];
    int rk[8];
#pragma unroll
    for (int k = 0; k < 8; k++) {
        int i = tid + k * 256;
        if (i < cntT) {
            e[k] = pairs1[start + i];
            rk[k] = atomicAdd(&cnt[(int)(e[k] >> 53) & 63], 1);
        }
    }
    __syncthreads();
    if (tid == 0) {
        int acc = 0;
        for (int s = 0; s < FINES_PER_SB; s++) { off[s] = acc; acc += cnt[s]; }
        off[FINES_PER_SB] = acc;
    }
    __syncthreads();
    if (tid < nF) gbase[tid] = atomicAdd(&fineCursor[fineFirst + tid], cnt[tid]);
#pragma unroll
    for (int k = 0; k < 8; k++) {
        int i = tid + k * 256;
        if (i < cntT) staged[off[(int)(e[k] >> 53) & 63] + rk[k]] = e[k];
    }
    __syncthreads();
    int total = off[FINES_PER_SB];
    for (int i = tid; i < total; i += 256) {
        ull v = staged[i];
        int lb = (int)(v >> 53) & 63;
        pairs2[gbase[lb] + (i - off[lb])] = v;
    }
}

// ---------------- K5: per-fine-bucket bitonic sort (u64 key) + dedupe/sum + compact ----------------
__global__ void __launch_bounds__(256) k_sortbucket(const int* __restrict__ fineBase,
                                                    ull* __restrict__ pairs2,
                                                    int* __restrict__ uniqueCount) {
    int b = blockIdx.x;
    int start = fineBase[b];
    int n = fineBase[b + 1] - start;
    if (n > CAP3) n = CAP3;     // 45-sigma safety clamp
    int tid = threadIdx.x;
    if (n <= 0) { if (tid == 0) uniqueCount[b] = 0; return; }

    __shared__ ull s[CAP3];
    __shared__ int part[256];

    int m = 1; while (m < n) m <<= 1;
    for (int i = tid; i < m; i += 256)
        s[i] = (i < n) ? pairs2[start + i] : ~0ull;
    __syncthreads();

    for (int k = 2; k <= m; k <<= 1) {
        for (int j = k >> 1; j > 0; j >>= 1) {
            for (int i = tid; i < m; i += 256) {
                int ixj = i ^ j;
                if (ixj > i) {
                    bool up = ((i & k) == 0);
                    ull a = s[i], c = s[ixj];
                    if ((a > c) == up) { s[i] = c; s[ixj] = a; }
                }
            }
            __syncthreads();
        }
    }

    // head-flag count per thread chunk (keys = top 32 bits)
    int chunk = (m + 255) >> 8;
    int s0 = tid * chunk; if (s0 > m) s0 = m;
    int s1 = s0 + chunk;  if (s1 > m) s1 = m;
    int cnt = 0;
    for (int i = s0; i < s1; i++)
        if (i < n && (i == 0 || (s[i] >> 32) != (s[i - 1] >> 32))) cnt++;
    part[tid] = cnt;
    __syncthreads();
    for (int off = 1; off < 256; off <<= 1) {
        int add = (tid >= off) ? part[tid - off] : 0;
        __syncthreads();
        part[tid] += add;
        __syncthreads();
    }
    int pos = part[tid] - cnt;
    int total = part[255];

    for (int i = s0; i < s1; i++) {
        if (i < n && (i == 0 || (s[i] >> 32) != (s[i - 1] >> 32))) {
            float acc = __uint_as_float((unsigned)(s[i] & 0xFFFFFFFFu));
            for (int q = i + 1; q < n && (s[q] >> 32) == (s[i] >> 32); q++)
                acc += __uint_as_float((unsigned)(s[q] & 0xFFFFFFFFu));
            pairs2[start + pos] = (s[i] & 0xFFFFFFFF00000000ull) | (ull)__float_as_uint(acc);
            pos++;
        }
    }
    if (tid == 0) uniqueCount[b] = total;
}

// ---------------- K7: write compacted output (row, col, attr as f32) ----------------
__global__ void __launch_bounds__(256) k_writeout(const int* __restrict__ fineBase,
                                                  const int* __restrict__ uniqueCount,
                                                  const int* __restrict__ outBase,
                                                  const ull* __restrict__ pairs2,
                                                  float* __restrict__ out) {
    int b = blockIdx.x;
    int n = uniqueCount[b];
    int src = fineBase[b];
    int dst = outBase[b];
    for (int j = threadIdx.x; j < n; j += 256) {
        ull e = pairs2[src + j];
        int r = (int)(e >> 48);
        int c = (int)((e >> 32) & 0xFFFF);
        int q = dst + j;
        out[q]          = (float)r;
        out[E2 + q]     = (float)c;
        out[2 * E2 + q] = __uint_as_float((unsigned)(e & 0xFFFFFFFFu));
    }
}

extern "C" void kernel_launch(void* const* d_in, const int* in_sizes, int n_in,
                              void* d_out, int out_size, void* d_ws, size_t ws_size,
                              hipStream_t stream) {
    const int*   ei = (const int*)d_in[0];     // [2,E]: rows then cols
    const float* ea = (const float*)d_in[1];   // [E]
    const float* t  = (const float*)d_in[2];   // [1]
    float* out = (float*)d_out;                // 2*E2 indices + E2 attrs + 1 count

    // workspace layout (~41.6 MB, matches previously-validated footprint)
    int* fineCount   = (int*)d_ws;                    // 1250
    int* fineBase    = fineCount + NFINE;             // 1251
    int* fineCursor  = fineBase + NFINE + 1;          // 1250
    int* sbCursor    = fineCursor + NFINE;            // 32
    int* uniqueCount = sbCursor + 32;                 // 1250
    int* outBase     = uniqueCount + NFINE;           // 1251
    ull* pairs1 = (ull*)(((uintptr_t)(outBase + NFINE + 1) + 15) & ~(uintptr_t)15);
    ull* pairs2 = pairs1 + PAIRS_CAP;

    hipMemsetAsync(fineCount, 0, NFINE * sizeof(int), stream);

    k_fill<<<(3 * E2 / 4 + 255) / 256, 256, 0, stream>>>((float4*)out);
    k_histF<<<160, 1024, 0, stream>>>(ei, ea, t, fineCount);
    k_scan<<<1, 1024, 0, stream>>>(fineCount, NFINE, fineBase, fineCursor, sbCursor, nullptr);
    k_part1<<<E_IN / 1024, 256, 0, stream>>>(ei, ea, t, sbCursor, pairs1);
    k_part2<<<NSB * P2_TILES, 256, 0, stream>>>(fineBase, fineCursor, pairs1, pairs2);
    k_sortbucket<<<NFINE, 256, 0, stream>>>(fineBase, pairs2, uniqueCount);
    k_scan<<<1, 1024, 0, stream>>>(uniqueCount, NFINE, outBase, nullptr, nullptr, out + (size_t)3 * E2);
    k_writeout<<<NFINE, 256, 0, stream>>>(fineBase, uniqueCount, outBase, pairs2, out);
}

// Round 4
// 246.045 us; speedup vs baseline: 2.8633x; 1.7620x over previous
//
#include <hip/hip_runtime.h>
#include <stdint.h>

#define NN 40000            // N_NODES
#define E_IN 2560000        // input edges
#define E2 5120000          // 2*E_IN, padded output size
#define NFINE 1250          // fine buckets: r>>5 (32 rows each)
#define NSB 20              // superbuckets: r>>11 (2048 rows each)
#define SB_SHIFT 11
#define FINES_PER_SB 64
#define P2_TILES 68         // 68*2048 = 139264 >= max superbucket count
#define CAP3 3072           // fine-bucket capacity (mean 2048, sigma 45 -> 22 sigma)
#define CAPROW 256          // per-row capacity (Poisson(64) -> 24 sigma)
#define PAIRS_CAP 2600000

typedef unsigned long long ull;

// ---------------- K0: fill output padding: indices=-1, attrs=0 ----------------
__global__ void k_fill(float4* __restrict__ out) {
    int i = blockIdx.x * blockDim.x + threadIdx.x;      // 3*E2/4 = 3,840,000
    if (i >= 3 * E2 / 4) return;
    float v = (i < 2 * E2 / 4) ? -1.0f : 0.0f;
    out[i] = make_float4(v, v, v, v);
}

// ---------------- K1: fine-bucket histogram (LDS sub-hist) ----------------
__global__ void __launch_bounds__(1024) k_histF(const int* __restrict__ ei,
                                                const float* __restrict__ ea,
                                                const float* __restrict__ t,
                                                int* __restrict__ fineCount) {
    __shared__ int h[NFINE];
    int tid = threadIdx.x;
    for (int j = tid; j < NFINE; j += 1024) h[j] = 0;
    __syncthreads();
    float t0 = t[0];
    for (int i = blockIdx.x * 1024 + tid; i < E_IN; i += 160 * 1024) {
        float a = ea[i];
        if (a <= t0) {
            int r = ei[i], c = ei[E_IN + i];
            atomicAdd(&h[r >> 5], 1);
            atomicAdd(&h[c >> 5], 1);
        }
    }
    __syncthreads();
    for (int j = tid; j < NFINE; j += 1024) {
        int v = h[j];
        if (v) atomicAdd(&fineCount[j], v);
    }
}

// ---------------- K2: single-block exclusive scan over n<=2048 ----------------
__global__ void __launch_bounds__(1024) k_scan(const int* __restrict__ in, int n,
                                               int* __restrict__ outExcl,
                                               int* __restrict__ outCursor,
                                               int* __restrict__ sbCursorOut,
                                               float* __restrict__ totalDst) {
    __shared__ int partial[1024];
    int tid = threadIdx.x;
    int i0 = 2 * tid, i1 = 2 * tid + 1;
    int v0 = (i0 < n) ? in[i0] : 0;
    int v1 = (i1 < n) ? in[i1] : 0;
    int sum = v0 + v1;
    partial[tid] = sum;
    __syncthreads();
    for (int off = 1; off < 1024; off <<= 1) {
        int add = (tid >= off) ? partial[tid - off] : 0;
        __syncthreads();
        partial[tid] += add;
        __syncthreads();
    }
    int base = partial[tid] - sum;
    if (i0 < n) { outExcl[i0] = base;      if (outCursor) outCursor[i0] = base; }
    if (i1 < n) { outExcl[i1] = base + v0; if (outCursor) outCursor[i1] = base + v0; }
    if (tid == 1023) {
        outExcl[n] = partial[1023];
        if (totalDst) totalDst[0] = (float)partial[1023];
    }
    if (sbCursorOut) {
        __syncthreads();
        if (tid < NSB) sbCursorOut[tid] = outExcl[tid * FINES_PER_SB];
    }
}

// ---------------- K3: partition pass 1 — entries -> 20 superbuckets ----------------
__global__ void __launch_bounds__(256) k_part1(const int* __restrict__ ei,
                                               const float* __restrict__ ea,
                                               const float* __restrict__ t,
                                               int* __restrict__ sbCursor,
                                               ull* __restrict__ pairs1) {
    __shared__ ull staged[2048];
    __shared__ int cnt[NSB], off[NSB + 1], gbase[NSB];
    int tid = threadIdx.x;
    if (tid < NSB) cnt[tid] = 0;
    __syncthreads();
    float t0 = t[0];
    int tileStart = blockIdx.x * 1024;          // 2500*1024 == E_IN exactly

    ull eA[4], eB[4];
    int rkA[4], rkB[4];
    bool keep[4];
#pragma unroll
    for (int k = 0; k < 4; k++) {
        int i = tileStart + tid + k * 256;
        float a = ea[i];
        keep[k] = (a <= t0);
        if (keep[k]) {
            int r = ei[i], c = ei[E_IN + i];
            unsigned ab = __float_as_uint(a);
            eA[k] = ((ull)(unsigned)r << 48) | ((ull)(unsigned)c << 32) | ab;
            eB[k] = ((ull)(unsigned)c << 48) | ((ull)(unsigned)r << 32) | ab;
            rkA[k] = atomicAdd(&cnt[r >> SB_SHIFT], 1);
            rkB[k] = atomicAdd(&cnt[c >> SB_SHIFT], 1);
        }
    }
    __syncthreads();
    if (tid == 0) {
        int acc = 0;
        for (int s = 0; s < NSB; s++) { off[s] = acc; acc += cnt[s]; }
        off[NSB] = acc;
    }
    __syncthreads();
    if (tid < NSB) gbase[tid] = atomicAdd(&sbCursor[tid], cnt[tid]);
#pragma unroll
    for (int k = 0; k < 4; k++) {
        if (keep[k]) {
            staged[off[(int)(eA[k] >> 59)] + rkA[k]] = eA[k];
            staged[off[(int)(eB[k] >> 59)] + rkB[k]] = eB[k];
        }
    }
    __syncthreads();
    int total = off[NSB];
    for (int i = tid; i < total; i += 256) {
        ull e = staged[i];
        int sb = (int)(e >> 59);
        pairs1[gbase[sb] + (i - off[sb])] = e;
    }
}

// ---------------- K4: partition pass 2 — superbucket -> 64 fine buckets ----------------
__global__ void __launch_bounds__(256) k_part2(const int* __restrict__ fineBase,
                                               int* __restrict__ fineCursor,
                                               const ull* __restrict__ pairs1,
                                               ull* __restrict__ pairs2) {
    int sb = blockIdx.x / P2_TILES;
    int tile = blockIdx.x % P2_TILES;
    int fineFirst = sb * FINES_PER_SB;
    int fineEnd = fineFirst + FINES_PER_SB; if (fineEnd > NFINE) fineEnd = NFINE;
    int nF = fineEnd - fineFirst;
    int sbStart = fineBase[fineFirst];
    int sbEnd = fineBase[fineEnd];
    int start = sbStart + tile * 2048;
    if (start >= sbEnd) return;
    int cntT = sbEnd - start; if (cntT > 2048) cntT = 2048;

    __shared__ ull staged[2048];
    __shared__ int cnt[FINES_PER_SB], off[FINES_PER_SB + 1], gbase[FINES_PER_SB];
    int tid = threadIdx.x;
    if (tid < FINES_PER_SB) cnt[tid] = 0;
    __syncthreads();

    ull e[8];
    int rk[8];
#pragma unroll
    for (int k = 0; k < 8; k++) {
        int i = tid + k * 256;
        if (i < cntT) {
            e[k] = pairs1[start + i];
            rk[k] = atomicAdd(&cnt[(int)(e[k] >> 53) & 63], 1);
        }
    }
    __syncthreads();
    if (tid == 0) {
        int acc = 0;
        for (int s = 0; s < FINES_PER_SB; s++) { off[s] = acc; acc += cnt[s]; }
        off[FINES_PER_SB] = acc;
    }
    __syncthreads();
    if (tid < nF) gbase[tid] = atomicAdd(&fineCursor[fineFirst + tid], cnt[tid]);
#pragma unroll
    for (int k = 0; k < 8; k++) {
        int i = tid + k * 256;
        if (i < cntT) staged[off[(int)(e[k] >> 53) & 63] + rk[k]] = e[k];
    }
    __syncthreads();
    int total = off[FINES_PER_SB];
    for (int i = tid; i < total; i += 256) {
        ull v = staged[i];
        int lb = (int)(v >> 53) & 63;
        pairs2[gbase[lb] + (i - off[lb])] = v;
    }
}

// ---------------- wave-level register bitonic sort + dedupe for one row ----------------
// Sorts dRow[0..nr) (nr <= 64*L) by the full u64 (top 32 bits = (r<<16)|c key),
// writes compacted unique (key, summed attr) back at dRow[0..total). One wave.
template<int L>
__device__ __forceinline__ int sort_row(ull* dRow, int nr, int lane) {
    const int m = 64 * L;
    ull e[L];
#pragma unroll
    for (int s = 0; s < L; s++) {
        int v = s * 64 + lane;
        e[s] = (v < nr) ? dRow[v] : ~0ull;
    }
    // bitonic over virtual index v = s*64 + lane
    for (int k = 2; k <= m; k <<= 1) {
        for (int j = k >> 1; j > 0; j >>= 1) {
            if (j >= 64) {
                int js = j >> 6;
#pragma unroll
                for (int s = 0; s < L; s++) {
                    int s2 = s ^ js;
                    if (s2 > s) {
                        bool up = (((s * 64) & k) == 0);   // k>=128: lane bits irrelevant
                        ull a = e[s], b = e[s2];
                        bool sw = up ? (a > b) : (a < b);
                        e[s]  = sw ? b : a;
                        e[s2] = sw ? a : b;
                    }
                }
            } else {
#pragma unroll
                for (int s = 0; s < L; s++) {
                    ull partner = __shfl_xor(e[s], j, 64);
                    int v = s * 64 + lane;
                    bool up = ((v & k) == 0);
                    bool lower = ((lane & j) == 0);
                    bool keepmin = (lower == up);
                    ull mn = e[s] < partner ? e[s] : partner;
                    ull mx = e[s] < partner ? partner : e[s];
                    e[s] = keepmin ? mn : mx;
                }
            }
        }
    }
    // head flags + ranks via ballot
    ull lmask = (1ull << lane) - 1;
    bool head[L];
    int rank[L];
    int base = 0;
#pragma unroll
    for (int s = 0; s < L; s++) {
        ull pv = __shfl_up(e[s], 1, 64);                 // lane0: garbage
        ull tl = (s > 0) ? __shfl(e[s - 1], 63, 64) : 0; // last of prev slot
        ull prev = (lane == 0) ? tl : pv;
        int v = s * 64 + lane;
        head[s] = (v < nr) && (v == 0 || (e[s] >> 32) != (prev >> 32));
        ull msk = __ballot(head[s]);
        rank[s] = base + __popcll(msk & lmask);
        base += __popcll(msk);
    }
    int total = base;
    // write sorted back (needed to read run members for duplicate sums)
#pragma unroll
    for (int s = 0; s < L; s++) {
        int v = s * 64 + lane;
        if (v < nr) dRow[v] = e[s];
    }
    __builtin_amdgcn_wave_barrier();
    float acc[L];
#pragma unroll
    for (int s = 0; s < L; s++) {
        if (head[s]) {
            float a = __uint_as_float((unsigned)(e[s] & 0xFFFFFFFFu));
            int v = s * 64 + lane;
            for (int q = v + 1; q < nr; q++) {
                ull x = dRow[q];
                if ((x >> 32) != (e[s] >> 32)) break;
                a += __uint_as_float((unsigned)(x & 0xFFFFFFFFu));
            }
            acc[s] = a;
        }
    }
    __builtin_amdgcn_wave_barrier();                     // all run reads before compacted writes
#pragma unroll
    for (int s = 0; s < L; s++) {
        if (head[s])
            dRow[rank[s]] = (e[s] & 0xFFFFFFFF00000000ull) | (ull)__float_as_uint(acc[s]);
    }
    return total;
}

// ---------------- K5: row-partition in LDS + per-row wave sort + compact ----------------
__global__ void __launch_bounds__(256) k_sortrows(const int* __restrict__ fineBase,
                                                  ull* __restrict__ pairs2,
                                                  int* __restrict__ uniqueCount) {
    int b = blockIdx.x;
    int start = fineBase[b];
    int n = fineBase[b + 1] - start;
    if (n > CAP3) n = CAP3;
    __shared__ ull d[CAP3];
    __shared__ int rcnt[32], rcur[32], roff[33], ucnt[32], ubase[32];
    int tid = threadIdx.x;
    if (tid < 32) { rcnt[tid] = 0; rcur[tid] = 0; }
    __syncthreads();
    // pass 1: row histogram (re-read from global, L2-hot)
    for (int i = tid; i < n; i += 256) {
        ull e = pairs2[start + i];
        atomicAdd(&rcnt[(int)(e >> 48) & 31], 1);
    }
    __syncthreads();
    if (tid == 0) {
        int acc = 0;
        for (int s = 0; s < 32; s++) { roff[s] = acc; acc += rcnt[s]; }
        roff[32] = acc;
    }
    __syncthreads();
    // pass 2: scatter into LDS grouped by row (order within row irrelevant)
    for (int i = tid; i < n; i += 256) {
        ull e = pairs2[start + i];
        int rr = (int)(e >> 48) & 31;
        int rk = atomicAdd(&rcur[rr], 1);
        d[roff[rr] + rk] = e;
    }
    __syncthreads();
    // phase B: one wave per row, register bitonic + dedupe
    int lane = tid & 63, wave = tid >> 6;
    for (int rr = wave; rr < 32; rr += 4) {
        int lo = roff[rr];
        int nr = roff[rr + 1] - lo;
        if (nr > CAPROW) nr = CAPROW;      // 24-sigma safety clamp
        int total;
        if (nr <= 64)       total = sort_row<1>(d + lo, nr, lane);
        else if (nr <= 128) total = sort_row<2>(d + lo, nr, lane);
        else                total = sort_row<4>(d + lo, nr, lane);
        if (lane == 0) ucnt[rr] = total;
    }
    __syncthreads();
    if (tid == 0) {
        int acc = 0;
        for (int s = 0; s < 32; s++) { ubase[s] = acc; acc += ucnt[s]; }
        uniqueCount[b] = acc;
    }
    __syncthreads();
    // copy compacted rows back contiguous per bucket
    for (int rr = wave; rr < 32; rr += 4) {
        int u = ucnt[rr], lo = roff[rr], ub = ubase[rr];
        for (int j = lane; j < u; j += 64)
            pairs2[start + ub + j] = d[lo + j];
    }
}

// ---------------- K7: write compacted output (row, col, attr as f32) ----------------
__global__ void __launch_bounds__(256) k_writeout(const int* __restrict__ fineBase,
                                                  const int* __restrict__ uniqueCount,
                                                  const int* __restrict__ outBase,
                                                  const ull* __restrict__ pairs2,
                                                  float* __restrict__ out) {
    int b = blockIdx.x;
    int n = uniqueCount[b];
    int src = fineBase[b];
    int dst = outBase[b];
    for (int j = threadIdx.x; j < n; j += 256) {
        ull e = pairs2[src + j];
        int r = (int)(e >> 48);
        int c = (int)((e >> 32) & 0xFFFF);
        int q = dst + j;
        out[q]          = (float)r;
        out[E2 + q]     = (float)c;
        out[2 * E2 + q] = __uint_as_float((unsigned)(e & 0xFFFFFFFFu));
    }
}

extern "C" void kernel_launch(void* const* d_in, const int* in_sizes, int n_in,
                              void* d_out, int out_size, void* d_ws, size_t ws_size,
                              hipStream_t stream) {
    const int*   ei = (const int*)d_in[0];     // [2,E]: rows then cols
    const float* ea = (const float*)d_in[1];   // [E]
    const float* t  = (const float*)d_in[2];   // [1]
    float* out = (float*)d_out;                // 2*E2 indices + E2 attrs + 1 count

    int* fineCount   = (int*)d_ws;                    // 1250
    int* fineBase    = fineCount + NFINE;             // 1251
    int* fineCursor  = fineBase + NFINE + 1;          // 1250
    int* sbCursor    = fineCursor + NFINE;            // 32
    int* uniqueCount = sbCursor + 32;                 // 1250
    int* outBase     = uniqueCount + NFINE;           // 1251
    ull* pairs1 = (ull*)(((uintptr_t)(outBase + NFINE + 1) + 15) & ~(uintptr_t)15);
    ull* pairs2 = pairs1 + PAIRS_CAP;

    hipMemsetAsync(fineCount, 0, NFINE * sizeof(int), stream);

    k_fill<<<(3 * E2 / 4 + 255) / 256, 256, 0, stream>>>((float4*)out);
    k_histF<<<160, 1024, 0, stream>>>(ei, ea, t, fineCount);
    k_scan<<<1, 1024, 0, stream>>>(fineCount, NFINE, fineBase, fineCursor, sbCursor, nullptr);
    k_part1<<<E_IN / 1024, 256, 0, stream>>>(ei, ea, t, sbCursor, pairs1);
    k_part2<<<NSB * P2_TILES, 256, 0, stream>>>(fineBase, fineCursor, pairs1, pairs2);
    k_sortrows<<<NFINE, 256, 0, stream>>>(fineBase, pairs2, uniqueCount);
    k_scan<<<1, 1024, 0, stream>>>(uniqueCount, NFINE, outBase, nullptr, nullptr, out + (size_t)3 * E2);
    k_writeout<<<NFINE, 256, 0, stream>>>(fineBase, uniqueCount, outBase, pairs2, out);
}

// Round 5
// 221.153 us; speedup vs baseline: 3.1856x; 1.1126x over previous
//
#include <hip/hip_runtime.h>
#include <stdint.h>

#define NN 40000            // N_NODES
#define E_IN 2560000        // input edges
#define E2 5120000          // 2*E_IN, padded output size
#define NFINE 1250          // fine buckets: r>>5 (32 rows each)
#define NSB 20              // superbuckets: r>>11 (2048 rows each)
#define SB_SHIFT 11
#define FINES_PER_SB 64
#define P2_TILES 68         // 68*2048 = 139264 >= max superbucket count
#define CAP3 3072           // fine-bucket capacity (mean 2048, sigma 45 -> 22 sigma)
#define CAPROW 256          // per-row capacity (Poisson(64) -> 24 sigma)
#define PAIRS_CAP 2600000

typedef unsigned long long ull;

// ---------------- K1: fine-bucket histogram (LDS sub-hist) ----------------
__global__ void __launch_bounds__(1024) k_histF(const int* __restrict__ ei,
                                                const float* __restrict__ ea,
                                                const float* __restrict__ t,
                                                int* __restrict__ fineCount) {
    __shared__ int h[NFINE];
    int tid = threadIdx.x;
    for (int j = tid; j < NFINE; j += 1024) h[j] = 0;
    __syncthreads();
    float t0 = t[0];
    for (int i = blockIdx.x * 1024 + tid; i < E_IN; i += 160 * 1024) {
        float a = ea[i];
        if (a <= t0) {
            int r = ei[i], c = ei[E_IN + i];
            atomicAdd(&h[r >> 5], 1);
            atomicAdd(&h[c >> 5], 1);
        }
    }
    __syncthreads();
    for (int j = tid; j < NFINE; j += 1024) {
        int v = h[j];
        if (v) atomicAdd(&fineCount[j], v);
    }
}

// ---------------- K2: single-block exclusive scan over n<=2048 ----------------
__global__ void __launch_bounds__(1024) k_scan(const int* __restrict__ in, int n,
                                               int* __restrict__ outExcl,
                                               int* __restrict__ outCursor,
                                               int* __restrict__ sbCursorOut,
                                               float* __restrict__ totalDst) {
    __shared__ int partial[1024];
    int tid = threadIdx.x;
    int i0 = 2 * tid, i1 = 2 * tid + 1;
    int v0 = (i0 < n) ? in[i0] : 0;
    int v1 = (i1 < n) ? in[i1] : 0;
    int sum = v0 + v1;
    partial[tid] = sum;
    __syncthreads();
    for (int off = 1; off < 1024; off <<= 1) {
        int add = (tid >= off) ? partial[tid - off] : 0;
        __syncthreads();
        partial[tid] += add;
        __syncthreads();
    }
    int base = partial[tid] - sum;
    if (i0 < n) { outExcl[i0] = base;      if (outCursor) outCursor[i0] = base; }
    if (i1 < n) { outExcl[i1] = base + v0; if (outCursor) outCursor[i1] = base + v0; }
    if (tid == 1023) {
        outExcl[n] = partial[1023];
        if (totalDst) totalDst[0] = (float)partial[1023];
    }
    if (sbCursorOut) {
        __syncthreads();
        if (tid < NSB) sbCursorOut[tid] = outExcl[tid * FINES_PER_SB];
    }
}

// ---------------- K3: partition pass 1 — entries -> 20 superbuckets ----------------
__global__ void __launch_bounds__(256) k_part1(const int* __restrict__ ei,
                                               const float* __restrict__ ea,
                                               const float* __restrict__ t,
                                               int* __restrict__ sbCursor,
                                               ull* __restrict__ pairs1) {
    __shared__ ull staged[2048];
    __shared__ int cnt[NSB], off[NSB + 1], gbase[NSB];
    int tid = threadIdx.x;
    if (tid < NSB) cnt[tid] = 0;
    __syncthreads();
    float t0 = t[0];
    int tileStart = blockIdx.x * 1024;          // 2500*1024 == E_IN exactly

    ull eA[4], eB[4];
    int rkA[4], rkB[4];
    bool keep[4];
#pragma unroll
    for (int k = 0; k < 4; k++) {
        int i = tileStart + tid + k * 256;
        float a = ea[i];
        keep[k] = (a <= t0);
        if (keep[k]) {
            int r = ei[i], c = ei[E_IN + i];
            unsigned ab = __float_as_uint(a);
            eA[k] = ((ull)(unsigned)r << 48) | ((ull)(unsigned)c << 32) | ab;
            eB[k] = ((ull)(unsigned)c << 48) | ((ull)(unsigned)r << 32) | ab;
            rkA[k] = atomicAdd(&cnt[r >> SB_SHIFT], 1);
            rkB[k] = atomicAdd(&cnt[c >> SB_SHIFT], 1);
        }
    }
    __syncthreads();
    if (tid == 0) {
        int acc = 0;
        for (int s = 0; s < NSB; s++) { off[s] = acc; acc += cnt[s]; }
        off[NSB] = acc;
    }
    __syncthreads();
    if (tid < NSB) gbase[tid] = atomicAdd(&sbCursor[tid], cnt[tid]);
#pragma unroll
    for (int k = 0; k < 4; k++) {
        if (keep[k]) {
            staged[off[(int)(eA[k] >> 59)] + rkA[k]] = eA[k];
            staged[off[(int)(eB[k] >> 59)] + rkB[k]] = eB[k];
        }
    }
    __syncthreads();
    int total = off[NSB];
    for (int i = tid; i < total; i += 256) {
        ull e = staged[i];
        int sb = (int)(e >> 59);
        pairs1[gbase[sb] + (i - off[sb])] = e;
    }
}

// ---------------- K4: partition pass 2 — superbucket -> 64 fine buckets ----------------
__global__ void __launch_bounds__(256) k_part2(const int* __restrict__ fineBase,
                                               int* __restrict__ fineCursor,
                                               const ull* __restrict__ pairs1,
                                               ull* __restrict__ pairs2) {
    int sb = blockIdx.x / P2_TILES;
    int tile = blockIdx.x % P2_TILES;
    int fineFirst = sb * FINES_PER_SB;
    int fineEnd = fineFirst + FINES_PER_SB; if (fineEnd > NFINE) fineEnd = NFINE;
    int nF = fineEnd - fineFirst;
    int sbStart = fineBase[fineFirst];
    int sbEnd = fineBase[fineEnd];
    int start = sbStart + tile * 2048;
    if (start >= sbEnd) return;
    int cntT = sbEnd - start; if (cntT > 2048) cntT = 2048;

    __shared__ ull staged[2048];
    __shared__ int cnt[FINES_PER_SB], off[FINES_PER_SB + 1], gbase[FINES_PER_SB];
    int tid = threadIdx.x;
    if (tid < FINES_PER_SB) cnt[tid] = 0;
    __syncthreads();

    ull e[8];
    int rk[8];
#pragma unroll
    for (int k = 0; k < 8; k++) {
        int i = tid + k * 256;
        if (i < cntT) {
            e[k] = pairs1[start + i];
            rk[k] = atomicAdd(&cnt[(int)(e[k] >> 53) & 63], 1);
        }
    }
    __syncthreads();
    if (tid == 0) {
        int acc = 0;
        for (int s = 0; s < FINES_PER_SB; s++) { off[s] = acc; acc += cnt[s]; }
        off[FINES_PER_SB] = acc;
    }
    __syncthreads();
    if (tid < nF) gbase[tid] = atomicAdd(&fineCursor[fineFirst + tid], cnt[tid]);
#pragma unroll
    for (int k = 0; k < 8; k++) {
        int i = tid + k * 256;
        if (i < cntT) staged[off[(int)(e[k] >> 53) & 63] + rk[k]] = e[k];
    }
    __syncthreads();
    int total = off[FINES_PER_SB];
    for (int i = tid; i < total; i += 256) {
        ull v = staged[i];
        int lb = (int)(v >> 53) & 63;
        pairs2[gbase[lb] + (i - off[lb])] = v;
    }
}

// ---------------- wave-level u32-key bitonic + dedupe for one row ----------------
// All entries in a row share r, so the sort key is just c (16b) packed with the
// source slot (8b): key = (c<<8)|v. Sort u32 keys (1 shfl/stage vs 2 for u64),
// then gather full entries from LDS by slot. Compacted result at dRow[0..total).
template<int L>
__device__ __forceinline__ int sort_row(ull* dRow, int nr, int lane) {
    const int m = 64 * L;
    unsigned key[L];
#pragma unroll
    for (int s = 0; s < L; s++) {
        int v = s * 64 + lane;
        key[s] = (v < nr) ? ((((unsigned)(dRow[v] >> 32) & 0xFFFFu) << 8) | (unsigned)v)
                          : 0xFFFFFFFFu;
    }
    for (int k = 2; k <= m; k <<= 1) {
        for (int j = k >> 1; j > 0; j >>= 1) {
            if (j >= 64) {
                int js = j >> 6;
#pragma unroll
                for (int s = 0; s < L; s++) {
                    int s2 = s ^ js;
                    if (s2 > s) {
                        bool up = (((s * 64) & k) == 0);   // k>=128: lane bits irrelevant
                        unsigned a = key[s], b = key[s2];
                        bool sw = up ? (a > b) : (a < b);
                        key[s]  = sw ? b : a;
                        key[s2] = sw ? a : b;
                    }
                }
            } else {
#pragma unroll
                for (int s = 0; s < L; s++) {
                    unsigned partner = __shfl_xor(key[s], j, 64);
                    int v = s * 64 + lane;
                    bool up = ((v & k) == 0);
                    bool lower = ((lane & j) == 0);
                    bool keepmin = (lower == up);
                    unsigned mn = key[s] < partner ? key[s] : partner;
                    unsigned mx = key[s] < partner ? partner : key[s];
                    key[s] = keepmin ? mn : mx;
                }
            }
        }
    }
    // head flags + ranks via ballot (compare c = key>>8)
    ull lmask = (1ull << lane) - 1;
    bool head[L];
    int rank[L];
    int base = 0;
#pragma unroll
    for (int s = 0; s < L; s++) {
        unsigned pv = __shfl_up(key[s], 1, 64);
        unsigned tl = (s > 0) ? __shfl(key[s - 1], 63, 64) : 0u;
        unsigned prev = (lane == 0) ? tl : pv;
        int v = s * 64 + lane;
        head[s] = (key[s] != 0xFFFFFFFFu) && (v == 0 || (key[s] >> 8) != (prev >> 8));
        ull msk = __ballot(head[s]);
        rank[s] = base + __popcll(msk & lmask);
        base += __popcll(msk);
    }
    int total = base;
    // gather full entries by source slot
    ull full[L];
#pragma unroll
    for (int s = 0; s < L; s++)
        full[s] = (key[s] != 0xFFFFFFFFu) ? dRow[key[s] & 255u] : 0ull;
    __builtin_amdgcn_wave_barrier();     // all gathers issued before overwrite (DS in-order per wave)
    // write sorted order back (needed to walk duplicate runs)
#pragma unroll
    for (int s = 0; s < L; s++) {
        int v = s * 64 + lane;
        if (v < nr) dRow[v] = full[s];
    }
    __builtin_amdgcn_wave_barrier();
    float acc[L];
#pragma unroll
    for (int s = 0; s < L; s++) {
        if (head[s]) {
            float a = __uint_as_float((unsigned)(full[s] & 0xFFFFFFFFu));
            int v = s * 64 + lane;
            for (int q = v + 1; q < nr; q++) {
                ull x = dRow[q];
                if ((x >> 32) != (full[s] >> 32)) break;
                a += __uint_as_float((unsigned)(x & 0xFFFFFFFFu));
            }
            acc[s] = a;
        }
    }
    __builtin_amdgcn_wave_barrier();     // all run reads before compacted writes
#pragma unroll
    for (int s = 0; s < L; s++) {
        if (head[s])
            dRow[rank[s]] = (full[s] & 0xFFFFFFFF00000000ull) | (ull)__float_as_uint(acc[s]);
    }
    return total;
}

// ---------------- K5: row-partition in LDS + per-row wave sort + compact ----------------
__global__ void __launch_bounds__(256) k_sortrows(const int* __restrict__ fineBase,
                                                  ull* __restrict__ pairs2,
                                                  int* __restrict__ uniqueCount) {
    int b = blockIdx.x;
    int start = fineBase[b];
    int n = fineBase[b + 1] - start;
    if (n > CAP3) n = CAP3;
    __shared__ ull d[CAP3];
    __shared__ int rcnt[32], roff[33], ucnt[32], ubase[32];
    int tid = threadIdx.x;
    if (tid < 32) rcnt[tid] = 0;
    __syncthreads();
    // single global read: stage entries in regs, rank via LDS atomics
    ull e[12];                              // 256*12 = 3072 = CAP3
    int rk[12];
#pragma unroll
    for (int k = 0; k < 12; k++) {
        int i = tid + k * 256;
        if (i < n) {
            e[k] = pairs2[start + i];
            rk[k] = atomicAdd(&rcnt[(int)(e[k] >> 48) & 31], 1);
        }
    }
    __syncthreads();
    if (tid == 0) {
        int acc = 0;
        for (int s = 0; s < 32; s++) { roff[s] = acc; acc += rcnt[s]; }
        roff[32] = acc;
    }
    __syncthreads();
#pragma unroll
    for (int k = 0; k < 12; k++) {
        int i = tid + k * 256;
        if (i < n) d[roff[(int)(e[k] >> 48) & 31] + rk[k]] = e[k];
    }
    __syncthreads();
    // one wave per row: register bitonic + dedupe
    int lane = tid & 63, wave = tid >> 6;
    for (int rr = wave; rr < 32; rr += 4) {
        int lo = roff[rr];
        int nr = roff[rr + 1] - lo;
        if (nr > CAPROW) nr = CAPROW;      // 24-sigma safety clamp
        int total;
        if (nr <= 64)       total = sort_row<1>(d + lo, nr, lane);
        else if (nr <= 128) total = sort_row<2>(d + lo, nr, lane);
        else                total = sort_row<4>(d + lo, nr, lane);
        if (lane == 0) ucnt[rr] = total;
    }
    __syncthreads();
    if (tid == 0) {
        int acc = 0;
        for (int s = 0; s < 32; s++) { ubase[s] = acc; acc += ucnt[s]; }
        uniqueCount[b] = acc;
    }
    __syncthreads();
    // copy compacted rows back contiguous per bucket
    for (int rr = wave; rr < 32; rr += 4) {
        int u = ucnt[rr], lo = roff[rr], ub = ubase[rr];
        for (int j = lane; j < u; j += 64)
            pairs2[start + ub + j] = d[lo + j];
    }
}

// ---------------- K6: fused pad-fill + write-out: every slot written once ----------------
__global__ void __launch_bounds__(256) k_outfill(const int* __restrict__ outBase,   // [NFINE+1]
                                                 const int* __restrict__ fineBase,  // [NFINE+1]
                                                 const ull* __restrict__ pairs2,
                                                 float* __restrict__ out) {
    __shared__ int sOB[NFINE + 1];
    int tid = threadIdx.x;
    for (int i = tid; i <= NFINE; i += 256) sOB[i] = outBase[i];
    __syncthreads();
    int j = blockIdx.x * 256 + tid;         // grid covers E2 exactly (20000*256)
    int T = sOB[NFINE];
    float r, c, a;
    if (j < T) {
        int lo = 0, hi = NFINE;             // invariant: sOB[lo] <= j < sOB[hi]
        while (hi - lo > 1) {
            int mid = (lo + hi) >> 1;
            if (sOB[mid] <= j) lo = mid; else hi = mid;
        }
        ull e = pairs2[fineBase[lo] + (j - sOB[lo])];
        r = (float)(int)(e >> 48);
        c = (float)(int)((e >> 32) & 0xFFFF);
        a = __uint_as_float((unsigned)(e & 0xFFFFFFFFu));
    } else {
        r = -1.0f; c = -1.0f; a = 0.0f;
    }
    out[j]          = r;
    out[E2 + j]     = c;
    out[2 * E2 + j] = a;
}

extern "C" void kernel_launch(void* const* d_in, const int* in_sizes, int n_in,
                              void* d_out, int out_size, void* d_ws, size_t ws_size,
                              hipStream_t stream) {
    const int*   ei = (const int*)d_in[0];     // [2,E]: rows then cols
    const float* ea = (const float*)d_in[1];   // [E]
    const float* t  = (const float*)d_in[2];   // [1]
    float* out = (float*)d_out;                // 2*E2 indices + E2 attrs + 1 count

    int* fineCount   = (int*)d_ws;                    // 1250
    int* fineBase    = fineCount + NFINE;             // 1251
    int* fineCursor  = fineBase + NFINE + 1;          // 1250
    int* sbCursor    = fineCursor + NFINE;            // 32
    int* uniqueCount = sbCursor + 32;                 // 1250
    int* outBase     = uniqueCount + NFINE;           // 1251
    ull* pairs1 = (ull*)(((uintptr_t)(outBase + NFINE + 1) + 15) & ~(uintptr_t)15);
    ull* pairs2 = pairs1 + PAIRS_CAP;

    hipMemsetAsync(fineCount, 0, NFINE * sizeof(int), stream);

    k_histF<<<160, 1024, 0, stream>>>(ei, ea, t, fineCount);
    k_scan<<<1, 1024, 0, stream>>>(fineCount, NFINE, fineBase, fineCursor, sbCursor, nullptr);
    k_part1<<<E_IN / 1024, 256, 0, stream>>>(ei, ea, t, sbCursor, pairs1);
    k_part2<<<NSB * P2_TILES, 256, 0, stream>>>(fineBase, fineCursor, pairs1, pairs2);
    k_sortrows<<<NFINE, 256, 0, stream>>>(fineBase, pairs2, uniqueCount);
    k_scan<<<1, 1024, 0, stream>>>(uniqueCount, NFINE, outBase, nullptr, nullptr, out + (size_t)3 * E2);
    k_outfill<<<E2 / 256, 256, 0, stream>>>(outBase, fineBase, pairs2, out);
}

// Round 7
// 198.978 us; speedup vs baseline: 3.5406x; 1.1114x over previous
//
#include <hip/hip_runtime.h>
#include <stdint.h>

#define NN 40000            // N_NODES
#define E_IN 2560000        // input edges
#define E2 5120000          // 2*E_IN, padded output size
#define NFINE 2500          // fine buckets: r>>4 (16 rows each)
#define NSB 20              // superbuckets: r>>11 (2048 rows each; sb19 partial)
#define SB_SHIFT 11
#define FINES_PER_SB 128
#define P2_TILES 66
#define SBCAP (P2_TILES*2048)  // 135168: mean 131072 + ~11 sigma (sigma~360)
#define CAPB 1280           // fine region: mean 1024 + 8 sigma (sigma~32)
#define CAPROW 256          // per-row safety clamp

typedef unsigned long long ull;

// ---------------- K0: init cursors to fixed region bases ----------------
__global__ void k_init(int* __restrict__ sbCursor, int* __restrict__ fineCursor) {
    int tid = threadIdx.x;
    for (int f = tid; f < NFINE; f += 256) fineCursor[f] = f * CAPB;
    if (tid < NSB) sbCursor[tid] = tid * SBCAP;
}

// ---------------- K1: partition pass 1 — entries -> 20 fixed superbucket regions ----------------
__global__ void __launch_bounds__(256) k_part1(const int* __restrict__ ei,
                                               const float* __restrict__ ea,
                                               const float* __restrict__ t,
                                               int* __restrict__ sbCursor,
                                               ull* __restrict__ pairs1) {
    __shared__ ull staged[2048];
    __shared__ int cnt[NSB], off[NSB + 1], gbase[NSB];
    int tid = threadIdx.x;
    if (tid < NSB) cnt[tid] = 0;
    __syncthreads();
    float t0 = t[0];
    int tileStart = blockIdx.x * 1024;          // 2500*1024 == E_IN exactly

    ull eA[4], eB[4];
    int rkA[4], rkB[4];
    bool keep[4];
#pragma unroll
    for (int k = 0; k < 4; k++) {
        int i = tileStart + tid + k * 256;
        float a = ea[i];
        keep[k] = (a <= t0);
        if (keep[k]) {
            int r = ei[i], c = ei[E_IN + i];
            unsigned ab = __float_as_uint(a);
            eA[k] = ((ull)(unsigned)r << 48) | ((ull)(unsigned)c << 32) | ab;
            eB[k] = ((ull)(unsigned)c << 48) | ((ull)(unsigned)r << 32) | ab;
            rkA[k] = atomicAdd(&cnt[r >> SB_SHIFT], 1);
            rkB[k] = atomicAdd(&cnt[c >> SB_SHIFT], 1);
        }
    }
    __syncthreads();
    if (tid == 0) {
        int acc = 0;
        for (int s = 0; s < NSB; s++) { off[s] = acc; acc += cnt[s]; }
        off[NSB] = acc;
    }
    __syncthreads();
    if (tid < NSB) gbase[tid] = atomicAdd(&sbCursor[tid], cnt[tid]);
#pragma unroll
    for (int k = 0; k < 4; k++) {
        if (keep[k]) {
            staged[off[(int)(eA[k] >> 59)] + rkA[k]] = eA[k];
            staged[off[(int)(eB[k] >> 59)] + rkB[k]] = eB[k];
        }
    }
    __syncthreads();
    int total = off[NSB];
    for (int i = tid; i < total; i += 256) {
        ull e = staged[i];
        int sb = (int)(e >> 59);
        pairs1[gbase[sb] + (i - off[sb])] = e;
    }
}

// ---------------- K2: partition pass 2 — superbucket -> 128 fixed fine regions ----------------
__global__ void __launch_bounds__(256) k_part2(const int* __restrict__ sbCursor,
                                               int* __restrict__ fineCursor,
                                               const ull* __restrict__ pairs1,
                                               ull* __restrict__ pairs2) {
    int sb = blockIdx.x / P2_TILES;
    int tile = blockIdx.x % P2_TILES;
    int regionBase = sb * SBCAP;
    int len = sbCursor[sb] - regionBase;        // final cursor = base + count
    if (len > SBCAP) len = SBCAP;               // defensive clamp
    int start = tile * 2048;
    if (start >= len) return;
    int cntT = len - start; if (cntT > 2048) cntT = 2048;
    const ull* src = pairs1 + regionBase + start;

    int fineFirst = sb * FINES_PER_SB;
    int nF = NFINE - fineFirst; if (nF > FINES_PER_SB) nF = FINES_PER_SB;

    __shared__ ull staged[2048];
    __shared__ int cnt[FINES_PER_SB], off[FINES_PER_SB + 1], gbase[FINES_PER_SB];
    int tid = threadIdx.x;
    if (tid < FINES_PER_SB) { cnt[tid] = 0; gbase[tid] = 0; }   // gbase zero-init: defense
    __syncthreads();

    ull e[8];
    int rk[8];
#pragma unroll
    for (int k = 0; k < 8; k++) {
        int i = tid + k * 256;
        if (i < cntT) {
            e[k] = src[i];
            rk[k] = atomicAdd(&cnt[(int)(e[k] >> 52) & 127], 1);
        }
    }
    __syncthreads();
    if (tid == 0) {
        int acc = 0;
        for (int s = 0; s < FINES_PER_SB; s++) { off[s] = acc; acc += cnt[s]; }
        off[FINES_PER_SB] = acc;
    }
    __syncthreads();
    if (tid < nF) gbase[tid] = atomicAdd(&fineCursor[fineFirst + tid], cnt[tid]);
#pragma unroll
    for (int k = 0; k < 8; k++) {
        int i = tid + k * 256;
        if (i < cntT) staged[off[(int)(e[k] >> 52) & 127] + rk[k]] = e[k];
    }
    __syncthreads();
    int total = off[FINES_PER_SB];
    for (int i = tid; i < total; i += 256) {
        ull v = staged[i];
        int lb = (int)(v >> 52) & 127;
        pairs2[gbase[lb] + (i - off[lb])] = v;
    }
}

// ---------------- wave-level u32-key bitonic + dedupe for one row ----------------
// Entries in a row share r; sort key = (c<<8)|slot (u32, 1 shfl/stage), gather
// full u64 entries by slot afterward. Compacted result at dRow[0..total).
template<int L>
__device__ __forceinline__ int sort_row(ull* dRow, int nr, int lane) {
    const int m = 64 * L;
    unsigned key[L];
#pragma unroll
    for (int s = 0; s < L; s++) {
        int v = s * 64 + lane;
        key[s] = (v < nr) ? ((((unsigned)(dRow[v] >> 32) & 0xFFFFu) << 8) | (unsigned)v)
                          : 0xFFFFFFFFu;
    }
    for (int k = 2; k <= m; k <<= 1) {
        for (int j = k >> 1; j > 0; j >>= 1) {
            if (j >= 64) {
                int js = j >> 6;
#pragma unroll
                for (int s = 0; s < L; s++) {
                    int s2 = s ^ js;
                    if (s2 > s) {
                        bool up = (((s * 64) & k) == 0);   // k>=128: lane bits irrelevant
                        unsigned a = key[s], b = key[s2];
                        bool sw = up ? (a > b) : (a < b);
                        key[s]  = sw ? b : a;
                        key[s2] = sw ? a : b;
                    }
                }
            } else {
#pragma unroll
                for (int s = 0; s < L; s++) {
                    unsigned partner = __shfl_xor(key[s], j, 64);
                    int v = s * 64 + lane;
                    bool up = ((v & k) == 0);
                    bool lower = ((lane & j) == 0);
                    bool keepmin = (lower == up);
                    unsigned mn = key[s] < partner ? key[s] : partner;
                    unsigned mx = key[s] < partner ? partner : key[s];
                    key[s] = keepmin ? mn : mx;
                }
            }
        }
    }
    // head flags + ranks via ballot (compare c = key>>8)
    ull lmask = (1ull << lane) - 1;
    bool head[L];
    int rank[L];
    int base = 0;
#pragma unroll
    for (int s = 0; s < L; s++) {
        unsigned pv = __shfl_up(key[s], 1, 64);
        unsigned tl = (s > 0) ? __shfl(key[s - 1], 63, 64) : 0u;
        unsigned prev = (lane == 0) ? tl : pv;
        int v = s * 64 + lane;
        head[s] = (key[s] != 0xFFFFFFFFu) && (v == 0 || (key[s] >> 8) != (prev >> 8));
        ull msk = __ballot(head[s]);
        rank[s] = base + __popcll(msk & lmask);
        base += __popcll(msk);
    }
    int total = base;
    // gather full entries by source slot
    ull full[L];
#pragma unroll
    for (int s = 0; s < L; s++)
        full[s] = (key[s] != 0xFFFFFFFFu) ? dRow[key[s] & 255u] : 0ull;
    __builtin_amdgcn_wave_barrier();     // gathers before overwrite (DS in-order per wave)
#pragma unroll
    for (int s = 0; s < L; s++) {
        int v = s * 64 + lane;
        if (v < nr) dRow[v] = full[s];
    }
    __builtin_amdgcn_wave_barrier();
    float acc[L];
#pragma unroll
    for (int s = 0; s < L; s++) {
        if (head[s]) {
            float a = __uint_as_float((unsigned)(full[s] & 0xFFFFFFFFu));
            int v = s * 64 + lane;
            for (int q = v + 1; q < nr; q++) {
                ull x = dRow[q];
                if ((x >> 32) != (full[s] >> 32)) break;
                a += __uint_as_float((unsigned)(x & 0xFFFFFFFFu));
            }
            acc[s] = a;
        }
    }
    __builtin_amdgcn_wave_barrier();     // run reads before compacted writes
#pragma unroll
    for (int s = 0; s < L; s++) {
        if (head[s])
            dRow[rank[s]] = (full[s] & 0xFFFFFFFF00000000ull) | (ull)__float_as_uint(acc[s]);
    }
    return total;
}

// ---------------- K3: row-partition in LDS + per-row wave sort + compact ----------------
__global__ void __launch_bounds__(256) k_sortrows(const int* __restrict__ fineCursor,
                                                  ull* __restrict__ pairs2,
                                                  int* __restrict__ uniqueCount) {
    int b = blockIdx.x;
    int base = b * CAPB;
    int n = fineCursor[b] - base;
    if (n > CAPB) n = CAPB;
    __shared__ ull d[CAPB];
    __shared__ int rcnt[16], roff[17], ucnt[16], ubase[16];
    int tid = threadIdx.x;
    if (tid < 16) rcnt[tid] = 0;
    __syncthreads();
    // single global read: stage entries in regs, rank via LDS atomics
    ull e[5];                               // 256*5 = 1280 = CAPB
    int rk[5];
#pragma unroll
    for (int k = 0; k < 5; k++) {
        int i = tid + k * 256;
        if (i < n) {
            e[k] = pairs2[base + i];
            rk[k] = atomicAdd(&rcnt[(int)(e[k] >> 48) & 15], 1);
        }
    }
    __syncthreads();
    if (tid == 0) {
        int acc = 0;
        for (int s = 0; s < 16; s++) { roff[s] = acc; acc += rcnt[s]; }
        roff[16] = acc;
    }
    __syncthreads();
#pragma unroll
    for (int k = 0; k < 5; k++) {
        int i = tid + k * 256;
        if (i < n) d[roff[(int)(e[k] >> 48) & 15] + rk[k]] = e[k];
    }
    __syncthreads();
    // one wave per row: register bitonic + dedupe (4 waves x 4 rows)
    int lane = tid & 63, wave = tid >> 6;
    for (int rr = wave; rr < 16; rr += 4) {
        int lo = roff[rr];
        int nr = roff[rr + 1] - lo;
        if (nr > CAPROW) nr = CAPROW;      // safety clamp
        int total;
        if (nr <= 64)       total = sort_row<1>(d + lo, nr, lane);
        else if (nr <= 128) total = sort_row<2>(d + lo, nr, lane);
        else                total = sort_row<4>(d + lo, nr, lane);
        if (lane == 0) ucnt[rr] = total;
    }
    __syncthreads();
    if (tid == 0) {
        int acc = 0;
        for (int s = 0; s < 16; s++) { ubase[s] = acc; acc += ucnt[s]; }
        uniqueCount[b] = acc;
    }
    __syncthreads();
    // copy compacted rows back contiguous per bucket
    for (int rr = wave; rr < 16; rr += 4) {
        int u = ucnt[rr], lo = roff[rr], ub = ubase[rr];
        for (int j = lane; j < u; j += 64)
            pairs2[base + ub + j] = d[lo + j];
    }
}

// ---------------- K4: single-block exclusive scan over n<=3072 ----------------
__global__ void __launch_bounds__(1024) k_scan(const int* __restrict__ in, int n,
                                               int* __restrict__ outExcl,
                                               float* __restrict__ totalDst) {
    __shared__ int partial[1024];
    int tid = threadIdx.x;
    int start = tid * 3;
    int v[3], sum = 0;
#pragma unroll
    for (int k = 0; k < 3; k++) {
        int i = start + k;
        int x = (i < n) ? in[i] : 0;
        v[k] = sum;                 // local exclusive prefix
        sum += x;
    }
    partial[tid] = sum;
    __syncthreads();
    for (int off = 1; off < 1024; off <<= 1) {
        int add = (tid >= off) ? partial[tid - off] : 0;
        __syncthreads();
        partial[tid] += add;
        __syncthreads();
    }
    int base = partial[tid] - sum;
#pragma unroll
    for (int k = 0; k < 3; k++) {
        int i = start + k;
        if (i < n) outExcl[i] = base + v[k];
    }
    if (tid == 1023) {
        outExcl[n] = partial[1023];
        if (totalDst) totalDst[0] = (float)partial[1023];
    }
}

// ---------------- K5: fused pad-fill + write-out, x4 vectorized ----------------
__global__ void __launch_bounds__(256) k_outfill(const int* __restrict__ outBase,   // [NFINE+1]
                                                 const ull* __restrict__ pairs2,
                                                 float* __restrict__ out) {
    __shared__ int sOB[NFINE + 1];
    int tid = threadIdx.x;
    for (int i = tid; i <= NFINE; i += 256) sOB[i] = outBase[i];
    __syncthreads();
    int j0 = (blockIdx.x * 256 + tid) * 4;      // grid covers E2 exactly (5000*1024)
    int T = sOB[NFINE];
    float rr[4], cc[4], aa[4];
    int lo = 0;
    if (j0 < T) {
        int hi = NFINE;                          // invariant: sOB[lo] <= j0 < sOB[hi]
        while (hi - lo > 1) {
            int mid = (lo + hi) >> 1;
            if (sOB[mid] <= j0) lo = mid; else hi = mid;
        }
    }
#pragma unroll
    for (int k = 0; k < 4; k++) {
        int j = j0 + k;
        if (j < T) {
            while (lo < NFINE - 1 && sOB[lo + 1] <= j) lo++;   // rare bucket advance
            ull e = pairs2[lo * CAPB + (j - sOB[lo])];
            rr[k] = (float)(int)(e >> 48);
            cc[k] = (float)(int)((e >> 32) & 0xFFFF);
            aa[k] = __uint_as_float((unsigned)(e & 0xFFFFFFFFu));
        } else { rr[k] = -1.0f; cc[k] = -1.0f; aa[k] = 0.0f; }
    }
    *(float4*)(out + j0)          = make_float4(rr[0], rr[1], rr[2], rr[3]);
    *(float4*)(out + E2 + j0)     = make_float4(cc[0], cc[1], cc[2], cc[3]);
    *(float4*)(out + 2 * E2 + j0) = make_float4(aa[0], aa[1], aa[2], aa[3]);
}

extern "C" void kernel_launch(void* const* d_in, const int* in_sizes, int n_in,
                              void* d_out, int out_size, void* d_ws, size_t ws_size,
                              hipStream_t stream) {
    const int*   ei = (const int*)d_in[0];     // [2,E]: rows then cols
    const float* ea = (const float*)d_in[1];   // [E]
    const float* t  = (const float*)d_in[2];   // [1]
    float* out = (float*)d_out;                // 2*E2 indices + E2 attrs + 1 count

    // ws: small arrays + pairs2 fixed regions (~25.7 MB, under proven 41.8 MB)
    int* sbCursor    = (int*)d_ws;                    // 32
    int* fineCursor  = sbCursor + 32;                 // 2500
    int* uniqueCount = fineCursor + NFINE;            // 2500
    int* outBase     = uniqueCount + NFINE;           // 2501
    ull* pairs2 = (ull*)(((uintptr_t)(outBase + NFINE + 1) + 15) & ~(uintptr_t)15);  // 2500*CAPB

    // pairs1 lives in d_out (20*SBCAP*8 = 21.6 MB < 61.4 MB): dead before k_outfill
    ull* pairs1 = (ull*)d_out;

    k_init<<<1, 256, 0, stream>>>(sbCursor, fineCursor);
    k_part1<<<E_IN / 1024, 256, 0, stream>>>(ei, ea, t, sbCursor, pairs1);
    k_part2<<<NSB * P2_TILES, 256, 0, stream>>>(sbCursor, fineCursor, pairs1, pairs2);
    k_sortrows<<<NFINE, 256, 0, stream>>>(fineCursor, pairs2, uniqueCount);
    k_scan<<<1, 1024, 0, stream>>>(uniqueCount, NFINE, outBase, out + (size_t)3 * E2);
    k_outfill<<<E2 / 1024, 256, 0, stream>>>(outBase, pairs2, out);
}